// Round 1
// baseline (7476.089 us; speedup 1.0000x reference)
//
#include <hip/hip_runtime.h>
#include <cmath>

#define S_LEN 2048
#define DMODEL 4096
#define NH 32
#define HDIM 128
#define HEAVY 256
#define RECENT 256
#define ATTN_SCALE 0.08838834764831845f  // 1/sqrt(128)

// ---------------- fp32 GEMM: C[M][N] = A[M][K] * B[N][K]^T ----------------
__global__ __launch_bounds__(256) void sgemm_bt(const float* __restrict__ A,
                                                const float* __restrict__ B,
                                                float* __restrict__ C,
                                                int M, int N, int K) {
  __shared__ float As[16][132];
  __shared__ float Bs[16][132];
  const int tid = threadIdx.x;
  const int tx = tid & 15, ty = tid >> 4;
  const int row0 = blockIdx.y * 128, col0 = blockIdx.x * 128;
  const int lr = tid >> 1;       // 0..127
  const int lk = (tid & 1) * 8;  // 0 or 8
  float acc[8][8] = {{0.f}};
  for (int k0 = 0; k0 < K; k0 += 16) {
    float4 a0 = *reinterpret_cast<const float4*>(&A[(size_t)(row0 + lr) * K + k0 + lk]);
    float4 a1 = *reinterpret_cast<const float4*>(&A[(size_t)(row0 + lr) * K + k0 + lk + 4]);
    float4 b0 = *reinterpret_cast<const float4*>(&B[(size_t)(col0 + lr) * K + k0 + lk]);
    float4 b1 = *reinterpret_cast<const float4*>(&B[(size_t)(col0 + lr) * K + k0 + lk + 4]);
    __syncthreads();
    As[lk + 0][lr] = a0.x; As[lk + 1][lr] = a0.y; As[lk + 2][lr] = a0.z; As[lk + 3][lr] = a0.w;
    As[lk + 4][lr] = a1.x; As[lk + 5][lr] = a1.y; As[lk + 6][lr] = a1.z; As[lk + 7][lr] = a1.w;
    Bs[lk + 0][lr] = b0.x; Bs[lk + 1][lr] = b0.y; Bs[lk + 2][lr] = b0.z; Bs[lk + 3][lr] = b0.w;
    Bs[lk + 4][lr] = b1.x; Bs[lk + 5][lr] = b1.y; Bs[lk + 6][lr] = b1.z; Bs[lk + 7][lr] = b1.w;
    __syncthreads();
#pragma unroll
    for (int kk = 0; kk < 16; kk++) {
      float4 a04 = *reinterpret_cast<const float4*>(&As[kk][ty * 8]);
      float4 a14 = *reinterpret_cast<const float4*>(&As[kk][ty * 8 + 4]);
      float4 b04 = *reinterpret_cast<const float4*>(&Bs[kk][tx * 8]);
      float4 b14 = *reinterpret_cast<const float4*>(&Bs[kk][tx * 8 + 4]);
      float a[8] = {a04.x, a04.y, a04.z, a04.w, a14.x, a14.y, a14.z, a14.w};
      float b[8] = {b04.x, b04.y, b04.z, b04.w, b14.x, b14.y, b14.z, b14.w};
#pragma unroll
      for (int i = 0; i < 8; i++)
#pragma unroll
        for (int j = 0; j < 8; j++) acc[i][j] = fmaf(a[i], b[j], acc[i][j]);
    }
  }
  for (int i = 0; i < 8; i++) {
    float4 c0 = make_float4(acc[i][0], acc[i][1], acc[i][2], acc[i][3]);
    float4 c1 = make_float4(acc[i][4], acc[i][5], acc[i][6], acc[i][7]);
    *reinterpret_cast<float4*>(&C[(size_t)(row0 + ty * 8 + i) * N + col0 + tx * 8]) = c0;
    *reinterpret_cast<float4*>(&C[(size_t)(row0 + ty * 8 + i) * N + col0 + tx * 8 + 4]) = c1;
  }
}

// ---------------- RoPE (in-place on Q and K) ----------------
__global__ void rope_kernel(float* __restrict__ Q, float* __restrict__ Km,
                            const int* __restrict__ pos) {
  int idx = blockIdx.x * blockDim.x + threadIdx.x;
  if (idx >= S_LEN * NH * 64) return;
  int d = idx & 63;
  int h = (idx >> 6) & 31;
  int r = idx >> 11;
  float p = (float)pos[r];
  float invf = (float)pow(10000.0, -(double)(2 * d) / 128.0);
  float ang = p * invf;  // fp32 multiply, like reference
  float c = cosf(ang), s = sinf(ang);
  size_t base = (size_t)r * DMODEL + h * HDIM + d;
  float q1 = Q[base], q2 = Q[base + 64];
  Q[base] = q1 * c - q2 * s;
  Q[base + 64] = q2 * c + q1 * s;
  float k1 = Km[base], k2 = Km[base + 64];
  Km[base] = k1 * c - k2 * s;
  Km[base + 64] = k2 * c + k1 * s;
}

// ---------------- pass A: per-row LSE (causal) ----------------
// block: 256 threads; 64 q-rows per block; 4 lanes per row split D into 32-chunks
__global__ __launch_bounds__(256) void attn_lse(const float* __restrict__ Q,
                                                const float* __restrict__ Kmat,
                                                float* __restrict__ lse) {
  __shared__ float Ks[32][HDIM];
  const int h = blockIdx.y;
  const int q0 = blockIdx.x * 64;
  const int tid = threadIdx.x;
  const int g = tid >> 2, sub = tid & 3;
  const int r = q0 + g;
  const float4* qp4 = reinterpret_cast<const float4*>(Q + (size_t)r * DMODEL + h * HDIM + sub * 32);
  float4 q4[8];
#pragma unroll
  for (int c = 0; c < 8; c++) q4[c] = qp4[(c + 2 * sub) & 7];  // rotated to kill LDS conflicts
  float m = -INFINITY, l = 0.f;
  for (int k0 = 0; k0 < q0 + 64; k0 += 32) {
    __syncthreads();
#pragma unroll
    for (int j = 0; j < 4; j++) {
      int idx4 = tid + j * 256;
      int kr = idx4 >> 5, c4 = idx4 & 31;
      reinterpret_cast<float4*>(&Ks[kr][0])[c4] =
          reinterpret_cast<const float4*>(&Kmat[(size_t)(k0 + kr) * DMODEL + h * HDIM])[c4];
    }
    __syncthreads();
    const int kend = min(32, r - k0 + 1);
    for (int kk = 0; kk < kend; kk++) {
      const float4* kp4 = reinterpret_cast<const float4*>(&Ks[kk][sub * 32]);
      float acc = 0.f;
#pragma unroll
      for (int c = 0; c < 8; c++) {
        float4 kv = kp4[(c + 2 * sub) & 7];
        float4 qv = q4[c];
        acc = fmaf(qv.x, kv.x, acc);
        acc = fmaf(qv.y, kv.y, acc);
        acc = fmaf(qv.z, kv.z, acc);
        acc = fmaf(qv.w, kv.w, acc);
      }
      acc += __shfl_xor(acc, 1);
      acc += __shfl_xor(acc, 2);
      const float s = acc * ATTN_SCALE;
      if (s > m) {
        l = l * expf(m - s) + 1.f;
        m = s;
      } else {
        l += expf(s - m);
      }
    }
  }
  if (sub == 0) lse[(size_t)h * S_LEN + r] = m + logf(l);
}

// ---------------- pass B: normalized P, P*V, column-sum partials ----------------
__global__ __launch_bounds__(256) void attn_pv(const float* __restrict__ Q,
                                               const float* __restrict__ Kmat,
                                               const float* __restrict__ V,
                                               const float* __restrict__ lse,
                                               float* __restrict__ AO,
                                               float* __restrict__ score_part) {
  __shared__ float Ks[32][HDIM];
  __shared__ float Vs[32][HDIM];
  __shared__ float sblk[32][4];
  const int h = blockIdx.y;
  const int q0 = blockIdx.x * 64;
  const int tid = threadIdx.x;
  const int g = tid >> 2, sub = tid & 3;
  const int wv = tid >> 6;   // wave id 0..3
  const int lane = tid & 63;
  const int r = q0 + g;
  const float4* qp4 = reinterpret_cast<const float4*>(Q + (size_t)r * DMODEL + h * HDIM + sub * 32);
  float4 q4[8], o4[8];
#pragma unroll
  for (int c = 0; c < 8; c++) {
    q4[c] = qp4[(c + 2 * sub) & 7];
    o4[c] = make_float4(0.f, 0.f, 0.f, 0.f);
  }
  const float myLse = lse[(size_t)h * S_LEN + r];
  float* spp = score_part + ((size_t)blockIdx.x * NH + h) * S_LEN;
  for (int k0 = 0; k0 < q0 + 64; k0 += 32) {
    __syncthreads();
#pragma unroll
    for (int j = 0; j < 4; j++) {
      int idx4 = tid + j * 256;
      int kr = idx4 >> 5, c4 = idx4 & 31;
      reinterpret_cast<float4*>(&Ks[kr][0])[c4] =
          reinterpret_cast<const float4*>(&Kmat[(size_t)(k0 + kr) * DMODEL + h * HDIM])[c4];
      reinterpret_cast<float4*>(&Vs[kr][0])[c4] =
          reinterpret_cast<const float4*>(&V[(size_t)(k0 + kr) * DMODEL + h * HDIM])[c4];
    }
    if (tid < 128) sblk[tid >> 2][tid & 3] = 0.f;
    __syncthreads();
    // wave-uniform bound so whole-wave shuffles are safe
    const int kw = min(32, q0 + wv * 16 + 15 - k0 + 1);
    for (int kk = 0; kk < kw; kk++) {
      const float4* kp4 = reinterpret_cast<const float4*>(&Ks[kk][sub * 32]);
      float acc = 0.f;
#pragma unroll
      for (int c = 0; c < 8; c++) {
        float4 kv = kp4[(c + 2 * sub) & 7];
        float4 qv = q4[c];
        acc = fmaf(qv.x, kv.x, acc);
        acc = fmaf(qv.y, kv.y, acc);
        acc = fmaf(qv.z, kv.z, acc);
        acc = fmaf(qv.w, kv.w, acc);
      }
      acc += __shfl_xor(acc, 1);
      acc += __shfl_xor(acc, 2);
      const int k = k0 + kk;
      const float p = (k <= r) ? expf(acc * ATTN_SCALE - myLse) : 0.f;
      const float4* vp4 = reinterpret_cast<const float4*>(&Vs[kk][sub * 32]);
#pragma unroll
      for (int c = 0; c < 8; c++) {
        float4 vv = vp4[(c + 2 * sub) & 7];
        o4[c].x = fmaf(p, vv.x, o4[c].x);
        o4[c].y = fmaf(p, vv.y, o4[c].y);
        o4[c].z = fmaf(p, vv.z, o4[c].z);
        o4[c].w = fmaf(p, vv.w, o4[c].w);
      }
      // deterministic per-wave column sum (p duplicated in 4 lanes -> *0.25)
      float ps = p;
      ps += __shfl_xor(ps, 4);
      ps += __shfl_xor(ps, 8);
      ps += __shfl_xor(ps, 16);
      ps += __shfl_xor(ps, 32);
      ps += __shfl_xor(ps, 1);
      ps += __shfl_xor(ps, 2);
      if (lane == 0) sblk[kk][wv] = ps * 0.25f;
    }
    __syncthreads();
    if (tid < 32) spp[k0 + tid] = sblk[tid][0] + sblk[tid][1] + sblk[tid][2] + sblk[tid][3];
  }
  float4* op4 = reinterpret_cast<float4*>(AO + (size_t)r * DMODEL + h * HDIM + sub * 32);
#pragma unroll
  for (int c = 0; c < 8; c++) op4[(c + 2 * sub) & 7] = o4[c];
}

// ---------------- reduce column-sum partials ----------------
__global__ void reduce_scores(const float* __restrict__ score_part, float* __restrict__ scores) {
  int idx = blockIdx.x * blockDim.x + threadIdx.x;
  if (idx >= NH * S_LEN) return;
  int h = idx >> 11, k = idx & 2047;
  float s = 0.f;
  for (int qb = 0; qb < 32; qb++) s += score_part[((size_t)qb * NH + h) * S_LEN + k];
  scores[idx] = s;
}

// ---------------- per-head exact top-256 + mask + previous_scores ----------------
__global__ __launch_bounds__(256) void topk_mask_kernel(const float* __restrict__ scores,
                                                        float* __restrict__ out_mask,
                                                        float* __restrict__ prev_scores) {
  const int h = blockIdx.x;
  __shared__ unsigned sb[S_LEN - RECENT];  // 1792
  __shared__ int cnt_sh;
  const int NSEL = S_LEN - RECENT;
  const int tid = threadIdx.x;
  const float* sc = scores + (size_t)h * S_LEN;
  for (int i = tid; i < NSEL; i += 256) sb[i] = __float_as_uint(sc[i]);
  __syncthreads();
  // greedy bit-build: largest T with count(v >= T) >= HEAVY  (values are >= 0 floats)
  unsigned prefix = 0u;
  for (int b = 31; b >= 0; b--) {
    unsigned cand = prefix | (1u << b);
    if (tid == 0) cnt_sh = 0;
    __syncthreads();
    int c = 0;
    for (int i = tid; i < NSEL; i += 256) c += (sb[i] >= cand) ? 1 : 0;
    atomicAdd(&cnt_sh, c);
    __syncthreads();
    if (cnt_sh >= HEAVY) prefix = cand;
    __syncthreads();
  }
  // strictly-greater count
  if (tid == 0) cnt_sh = 0;
  __syncthreads();
  int c = 0;
  for (int i = tid; i < NSEL; i += 256) c += (sb[i] > prefix) ? 1 : 0;
  atomicAdd(&cnt_sh, c);
  __syncthreads();
  const int c1 = cnt_sh;
  float* mrow = out_mask + (size_t)h * (S_LEN + 1);
  float* prow = prev_scores + (size_t)h * S_LEN;
  for (int j = NSEL + tid; j < S_LEN + 1; j += 256) mrow[j] = 1.0f;
  for (int k = NSEL + tid; k < S_LEN; k += 256) prow[k] = sc[k];
  for (int i = tid; i < NSEL; i += 256) {
    bool sel = sb[i] > prefix;
    mrow[i] = sel ? 1.f : 0.f;
    prow[i] = sel ? sc[i] : 0.f;
  }
  __syncthreads();
  if (tid == 0) {  // ties at threshold: earliest index first (jax top_k stable order)
    int need = HEAVY - c1;
    for (int i = 0; i < NSEL && need > 0; i++) {
      if (sb[i] == prefix) { mrow[i] = 1.f; prow[i] = sc[i]; need--; }
    }
  }
}

extern "C" void kernel_launch(void* const* d_in, const int* in_sizes, int n_in,
                              void* d_out, int out_size, void* d_ws, size_t ws_size,
                              hipStream_t stream) {
  const float* hidden = (const float*)d_in[0];
  // d_in[1]: attention_mask (causal by construction; enforced via k<=r)
  const int* pos = (const int*)d_in[2];
  const float* Wq = (const float*)d_in[3];
  const float* Wk = (const float*)d_in[4];
  const float* Wv = (const float*)d_in[5];
  const float* Wo = (const float*)d_in[6];

  float* out0 = (float*)d_out;                                // 2048*4096
  float* out_mask = out0 + (size_t)S_LEN * DMODEL;            // 32*2049
  float* prev_scores = out_mask + (size_t)NH * (S_LEN + 1);   // 32*2048

  float* Q = (float*)d_ws;
  float* Km = Q + (size_t)S_LEN * DMODEL;
  float* V = Km + (size_t)S_LEN * DMODEL;
  float* AO = V + (size_t)S_LEN * DMODEL;
  float* lse = AO + (size_t)S_LEN * DMODEL;
  float* score_part = lse + (size_t)NH * S_LEN;
  float* scores = score_part + (size_t)32 * NH * S_LEN;

  dim3 gg(DMODEL / 128, S_LEN / 128);
  sgemm_bt<<<gg, 256, 0, stream>>>(hidden, Wq, Q, S_LEN, DMODEL, DMODEL);
  sgemm_bt<<<gg, 256, 0, stream>>>(hidden, Wk, Km, S_LEN, DMODEL, DMODEL);
  sgemm_bt<<<gg, 256, 0, stream>>>(hidden, Wv, V, S_LEN, DMODEL, DMODEL);

  int rope_total = S_LEN * NH * 64;
  rope_kernel<<<(rope_total + 255) / 256, 256, 0, stream>>>(Q, Km, pos);

  dim3 ga(S_LEN / 64, NH);
  attn_lse<<<ga, 256, 0, stream>>>(Q, Km, lse);
  hipMemsetAsync(score_part, 0, (size_t)32 * NH * S_LEN * sizeof(float), stream);
  attn_pv<<<ga, 256, 0, stream>>>(Q, Km, V, lse, AO, score_part);
  reduce_scores<<<(NH * S_LEN + 255) / 256, 256, 0, stream>>>(score_part, scores);
  topk_mask_kernel<<<NH, 256, 0, stream>>>(scores, out_mask, prev_scores);

  sgemm_bt<<<gg, 256, 0, stream>>>(AO, Wo, out0, S_LEN, DMODEL, DMODEL);
}

// Round 4
// 2080.635 us; speedup vs baseline: 3.5932x; 3.5932x over previous
//
#include <hip/hip_runtime.h>
#include <hip/hip_bf16.h>
#include <cmath>

#define S_LEN 2048
#define DMODEL 4096
#define NH 32
#define HDIM 128
#define HEAVY 256
#define RECENT 256
#define ATTN_SCALE 0.08838834764831845f  // 1/sqrt(128)
#define NEGBIG -3.0e38f
#define MB (1024ull * 1024ull)

typedef __attribute__((ext_vector_type(8))) short short8v;
typedef __attribute__((ext_vector_type(4))) short short4v;
typedef __attribute__((ext_vector_type(4))) float floatx4;

__device__ inline ushort f2bf(float x) {
  __hip_bfloat16 h = __float2bfloat16(x);
  return __builtin_bit_cast(ushort, h);
}
__device__ inline float bf2f(ushort u) {
  __hip_bfloat16 h = __builtin_bit_cast(__hip_bfloat16, u);
  return __bfloat162float(h);
}
struct Split3 {
  short a, b, c;
};
__device__ inline Split3 split3(float x) {
  Split3 o;
  ushort u1 = f2bf(x);
  float r1 = x - bf2f(u1);
  ushort u2 = f2bf(r1);
  float r2 = r1 - bf2f(u2);
  ushort u3 = f2bf(r2);
  o.a = (short)u1;
  o.b = (short)u2;
  o.c = (short)u3;
  return o;
}

// ===== 6-product (3-way split) fp32-class GEMM: C[M][N] = A[M][K]*B[N][K]^T =====
__global__ __launch_bounds__(256) void gemm6(const float* __restrict__ A,
                                             const float* __restrict__ B,
                                             float* __restrict__ C, int M, int N, int K) {
  __shared__ short Aa[128 * 40], Ab[128 * 40], Ac[128 * 40];
  __shared__ short Ba[128 * 40], Bb[128 * 40], Bc[128 * 40];
  const int tid = threadIdx.x;
  const int w = tid >> 6, l = tid & 63, g = l >> 4, ln = l & 15;
  const int wm = w >> 1, wn = w & 1;
  const int row0 = blockIdx.y * 128, col0 = blockIdx.x * 128;
  floatx4 acc[4][4] = {};
  for (int k0 = 0; k0 < K; k0 += 32) {
    __syncthreads();
#pragma unroll
    for (int i = 0; i < 4; i++) {
      int id = tid + i * 256;
      int r = id >> 3, c4 = id & 7;
      float4 av = *reinterpret_cast<const float4*>(&A[(size_t)(row0 + r) * K + k0 + c4 * 4]);
      float4 bv = *reinterpret_cast<const float4*>(&B[(size_t)(col0 + r) * K + k0 + c4 * 4]);
      float af[4] = {av.x, av.y, av.z, av.w};
      float bf[4] = {bv.x, bv.y, bv.z, bv.w};
      short4v a1, a2, a3, b1, b2, b3;
#pragma unroll
      for (int j = 0; j < 4; j++) {
        Split3 sa = split3(af[j]);
        Split3 sb = split3(bf[j]);
        a1[j] = sa.a; a2[j] = sa.b; a3[j] = sa.c;
        b1[j] = sb.a; b2[j] = sb.b; b3[j] = sb.c;
      }
      int o = r * 40 + c4 * 4;
      *reinterpret_cast<short4v*>(&Aa[o]) = a1;
      *reinterpret_cast<short4v*>(&Ab[o]) = a2;
      *reinterpret_cast<short4v*>(&Ac[o]) = a3;
      *reinterpret_cast<short4v*>(&Ba[o]) = b1;
      *reinterpret_cast<short4v*>(&Bb[o]) = b2;
      *reinterpret_cast<short4v*>(&Bc[o]) = b3;
    }
    __syncthreads();
#pragma unroll
    for (int i = 0; i < 4; i++) {
      int ar = (wm * 64 + i * 16 + ln) * 40 + g * 8;
      short8v a1 = *reinterpret_cast<const short8v*>(&Aa[ar]);
      short8v a2 = *reinterpret_cast<const short8v*>(&Ab[ar]);
      short8v a3 = *reinterpret_cast<const short8v*>(&Ac[ar]);
#pragma unroll
      for (int j = 0; j < 4; j++) {
        int br = (wn * 64 + j * 16 + ln) * 40 + g * 8;
        short8v b1 = *reinterpret_cast<const short8v*>(&Ba[br]);
        short8v b2 = *reinterpret_cast<const short8v*>(&Bb[br]);
        short8v b3 = *reinterpret_cast<const short8v*>(&Bc[br]);
        acc[i][j] = __builtin_amdgcn_mfma_f32_16x16x32_bf16(a1, b1, acc[i][j], 0, 0, 0);
        acc[i][j] = __builtin_amdgcn_mfma_f32_16x16x32_bf16(a1, b2, acc[i][j], 0, 0, 0);
        acc[i][j] = __builtin_amdgcn_mfma_f32_16x16x32_bf16(a2, b1, acc[i][j], 0, 0, 0);
        acc[i][j] = __builtin_amdgcn_mfma_f32_16x16x32_bf16(a1, b3, acc[i][j], 0, 0, 0);
        acc[i][j] = __builtin_amdgcn_mfma_f32_16x16x32_bf16(a2, b2, acc[i][j], 0, 0, 0);
        acc[i][j] = __builtin_amdgcn_mfma_f32_16x16x32_bf16(a3, b1, acc[i][j], 0, 0, 0);
      }
    }
  }
#pragma unroll
  for (int i = 0; i < 4; i++)
#pragma unroll
    for (int j = 0; j < 4; j++)
#pragma unroll
      for (int r = 0; r < 4; r++)
        C[(size_t)(row0 + wm * 64 + i * 16 + g * 4 + r) * N + col0 + wn * 64 + j * 16 + ln] =
            acc[i][j][r];
}

// ===== plain bf16 GEMM, fp32 out (Wo) =====
__global__ __launch_bounds__(256) void gemm_bf1(const float* __restrict__ A,
                                                const float* __restrict__ B,
                                                float* __restrict__ C, int M, int N, int K) {
  __shared__ short Ah[128 * 40];
  __shared__ short Bh[128 * 40];
  const int tid = threadIdx.x;
  const int w = tid >> 6, l = tid & 63, g = l >> 4, ln = l & 15;
  const int wm = w >> 1, wn = w & 1;
  const int row0 = blockIdx.y * 128, col0 = blockIdx.x * 128;
  floatx4 acc[4][4] = {};
  for (int k0 = 0; k0 < K; k0 += 32) {
    __syncthreads();
#pragma unroll
    for (int i = 0; i < 4; i++) {
      int id = tid + i * 256;
      int r = id >> 3, c4 = id & 7;
      float4 av = *reinterpret_cast<const float4*>(&A[(size_t)(row0 + r) * K + k0 + c4 * 4]);
      float4 bv = *reinterpret_cast<const float4*>(&B[(size_t)(col0 + r) * K + k0 + c4 * 4]);
      short4v ah, bh;
      ah[0] = (short)f2bf(av.x); ah[1] = (short)f2bf(av.y);
      ah[2] = (short)f2bf(av.z); ah[3] = (short)f2bf(av.w);
      bh[0] = (short)f2bf(bv.x); bh[1] = (short)f2bf(bv.y);
      bh[2] = (short)f2bf(bv.z); bh[3] = (short)f2bf(bv.w);
      *reinterpret_cast<short4v*>(&Ah[r * 40 + c4 * 4]) = ah;
      *reinterpret_cast<short4v*>(&Bh[r * 40 + c4 * 4]) = bh;
    }
    __syncthreads();
#pragma unroll
    for (int i = 0; i < 4; i++) {
      short8v a = *reinterpret_cast<const short8v*>(&Ah[(wm * 64 + i * 16 + ln) * 40 + g * 8]);
#pragma unroll
      for (int j = 0; j < 4; j++) {
        short8v b = *reinterpret_cast<const short8v*>(&Bh[(wn * 64 + j * 16 + ln) * 40 + g * 8]);
        acc[i][j] = __builtin_amdgcn_mfma_f32_16x16x32_bf16(a, b, acc[i][j], 0, 0, 0);
      }
    }
  }
#pragma unroll
  for (int i = 0; i < 4; i++)
#pragma unroll
    for (int j = 0; j < 4; j++)
#pragma unroll
      for (int r = 0; r < 4; r++)
        C[(size_t)(row0 + wm * 64 + i * 16 + g * 4 + r) * N + col0 + wn * 64 + j * 16 + ln] =
            acc[i][j][r];
}

// ===== plain bf16 GEMM, transposed bf16 out: Vt[n][m] = (A*B^T)[m][n] =====
__global__ __launch_bounds__(256) void gemm_vbt(const float* __restrict__ A,
                                                const float* __restrict__ B,
                                                ushort* __restrict__ Vt, int M, int N, int K) {
  __shared__ short Ah[128 * 40];
  __shared__ short Bh[128 * 40];
  const int tid = threadIdx.x;
  const int w = tid >> 6, l = tid & 63, g = l >> 4, ln = l & 15;
  const int wm = w >> 1, wn = w & 1;
  const int row0 = blockIdx.y * 128, col0 = blockIdx.x * 128;
  floatx4 acc[4][4] = {};
  for (int k0 = 0; k0 < K; k0 += 32) {
    __syncthreads();
#pragma unroll
    for (int i = 0; i < 4; i++) {
      int id = tid + i * 256;
      int r = id >> 3, c4 = id & 7;
      float4 av = *reinterpret_cast<const float4*>(&A[(size_t)(row0 + r) * K + k0 + c4 * 4]);
      float4 bv = *reinterpret_cast<const float4*>(&B[(size_t)(col0 + r) * K + k0 + c4 * 4]);
      short4v ah, bh;
      ah[0] = (short)f2bf(av.x); ah[1] = (short)f2bf(av.y);
      ah[2] = (short)f2bf(av.z); ah[3] = (short)f2bf(av.w);
      bh[0] = (short)f2bf(bv.x); bh[1] = (short)f2bf(bv.y);
      bh[2] = (short)f2bf(bv.z); bh[3] = (short)f2bf(bv.w);
      *reinterpret_cast<short4v*>(&Ah[r * 40 + c4 * 4]) = ah;
      *reinterpret_cast<short4v*>(&Bh[r * 40 + c4 * 4]) = bh;
    }
    __syncthreads();
#pragma unroll
    for (int i = 0; i < 4; i++) {
      short8v a = *reinterpret_cast<const short8v*>(&Ah[(wm * 64 + i * 16 + ln) * 40 + g * 8]);
#pragma unroll
      for (int j = 0; j < 4; j++) {
        short8v b = *reinterpret_cast<const short8v*>(&Bh[(wn * 64 + j * 16 + ln) * 40 + g * 8]);
        acc[i][j] = __builtin_amdgcn_mfma_f32_16x16x32_bf16(a, b, acc[i][j], 0, 0, 0);
      }
    }
  }
  // transposed bf16 store: Vt[(col0+wn*64+j*16+ln) * M + row0+wm*64+i*16+g*4 .. +3]
#pragma unroll
  for (int i = 0; i < 4; i++)
#pragma unroll
    for (int j = 0; j < 4; j++) {
      short4v o;
#pragma unroll
      for (int r = 0; r < 4; r++) o[r] = (short)f2bf(acc[i][j][r]);
      size_t n = col0 + wn * 64 + j * 16 + ln;
      size_t m0 = row0 + wm * 64 + i * 16 + g * 4;
      *reinterpret_cast<short4v*>(&Vt[n * M + m0]) = o;
    }
}

// ===== RoPE + 3-way split of Q,K =====
__global__ void rope_convert(const float* __restrict__ Q, const float* __restrict__ K,
                             const int* __restrict__ pos, short* __restrict__ Qa,
                             short* __restrict__ Qb, short* __restrict__ Qc,
                             short* __restrict__ Ka, short* __restrict__ Kb,
                             short* __restrict__ Kc) {
  int idx = blockIdx.x * blockDim.x + threadIdx.x;
  if (idx >= S_LEN * NH * 64) return;
  int d = idx & 63;
  int h = (idx >> 6) & 31;
  int r = idx >> 11;
  float p = (float)pos[r];
  float invf = (float)pow(10000.0, -(double)(2 * d) / 128.0);
  float ang = p * invf;
  float c = cosf(ang), s = sinf(ang);
  size_t base = (size_t)r * DMODEL + h * HDIM + d;
  float q1 = Q[base], q2 = Q[base + 64];
  float k1 = K[base], k2 = K[base + 64];
  float qa = q1 * c - q2 * s, qb = q2 * c + q1 * s;
  float ka = k1 * c - k2 * s, kb = k2 * c + k1 * s;
  Split3 t;
  t = split3(qa); Qa[base] = t.a; Qb[base] = t.b; Qc[base] = t.c;
  t = split3(qb); Qa[base + 64] = t.a; Qb[base + 64] = t.b; Qc[base + 64] = t.c;
  t = split3(ka); Ka[base] = t.a; Kb[base] = t.b; Kc[base] = t.c;
  t = split3(kb); Ka[base + 64] = t.a; Kb[base + 64] = t.b; Kc[base + 64] = t.c;
}

// ===== fused flash attention: 6-product QK^T + bf16 PV + exact colsums =====
__global__ __launch_bounds__(256) void attn_all6(
    const short* __restrict__ Qa, const short* __restrict__ Qb, const short* __restrict__ Qc,
    const short* __restrict__ Ka, const short* __restrict__ Kb, const short* __restrict__ Kc,
    const ushort* __restrict__ Vt, float* __restrict__ AO, float* __restrict__ score_part) {
  __shared__ short KaS[64 * 128], KbS[64 * 128], KcS[64 * 128];
  __shared__ short Ps[4 * 16 * 64];
  __shared__ float cs[4][64];
  const int h = blockIdx.y;
  const int q0 = blockIdx.x * 64;
  const int tid = threadIdx.x;
  const int w = tid >> 6, l = tid & 63, g = l >> 4, ln = l & 15;
  const int qrow = q0 + w * 16 + ln;
  short8v q1[4], q2[4], q3[4];
#pragma unroll
  for (int dc = 0; dc < 4; dc++) {
    size_t off = (size_t)qrow * DMODEL + h * HDIM + dc * 32 + g * 8;
    q1[dc] = *reinterpret_cast<const short8v*>(&Qa[off]);
    q2[dc] = *reinterpret_cast<const short8v*>(&Qb[off]);
    q3[dc] = *reinterpret_cast<const short8v*>(&Qc[off]);
  }
  float m_r[4], l_r[4];
#pragma unroll
  for (int r = 0; r < 4; r++) { m_r[r] = NEGBIG; l_r[r] = 0.f; }
  const int nkt = q0 / 64 + 1;

  // ---- loop 1: exact per-row max & sum ----
  for (int kt = 0; kt < nkt; kt++) {
    const int k0 = kt * 64;
    __syncthreads();
#pragma unroll
    for (int i = 0; i < 4; i++) {
      int id = tid + i * 256;
      int r = id >> 4, c = id & 15;
      size_t goff = (size_t)(k0 + r) * DMODEL + h * HDIM + c * 8;
      int didx = r * 128 + ((c * 8) ^ ((r & 7) << 3));
      *reinterpret_cast<short8v*>(&KaS[didx]) = *reinterpret_cast<const short8v*>(&Ka[goff]);
      *reinterpret_cast<short8v*>(&KbS[didx]) = *reinterpret_cast<const short8v*>(&Kb[goff]);
      *reinterpret_cast<short8v*>(&KcS[didx]) = *reinterpret_cast<const short8v*>(&Kc[goff]);
    }
    __syncthreads();
    float sv[4][4];
#pragma unroll
    for (int ct = 0; ct < 4; ct++) {
      floatx4 sacc = {};
      const int krow = ct * 16 + ln;
#pragma unroll
      for (int dc = 0; dc < 4; dc++) {
        int didx = krow * 128 + ((dc * 32 + g * 8) ^ ((krow & 7) << 3));
        short8v k1 = *reinterpret_cast<const short8v*>(&KaS[didx]);
        short8v k2 = *reinterpret_cast<const short8v*>(&KbS[didx]);
        short8v k3 = *reinterpret_cast<const short8v*>(&KcS[didx]);
        sacc = __builtin_amdgcn_mfma_f32_16x16x32_bf16(q1[dc], k1, sacc, 0, 0, 0);
        sacc = __builtin_amdgcn_mfma_f32_16x16x32_bf16(q1[dc], k2, sacc, 0, 0, 0);
        sacc = __builtin_amdgcn_mfma_f32_16x16x32_bf16(q2[dc], k1, sacc, 0, 0, 0);
        sacc = __builtin_amdgcn_mfma_f32_16x16x32_bf16(q1[dc], k3, sacc, 0, 0, 0);
        sacc = __builtin_amdgcn_mfma_f32_16x16x32_bf16(q2[dc], k2, sacc, 0, 0, 0);
        sacc = __builtin_amdgcn_mfma_f32_16x16x32_bf16(q3[dc], k1, sacc, 0, 0, 0);
      }
#pragma unroll
      for (int r = 0; r < 4; r++) {
        float s = sacc[r] * ATTN_SCALE;
        int key = k0 + ct * 16 + ln;
        int qq = q0 + w * 16 + g * 4 + r;
        sv[ct][r] = (key <= qq) ? s : NEGBIG;
      }
    }
#pragma unroll
    for (int r = 0; r < 4; r++) {
      float tmax = fmaxf(fmaxf(sv[0][r], sv[1][r]), fmaxf(sv[2][r], sv[3][r]));
      tmax = fmaxf(tmax, __shfl_xor(tmax, 1));
      tmax = fmaxf(tmax, __shfl_xor(tmax, 2));
      tmax = fmaxf(tmax, __shfl_xor(tmax, 4));
      tmax = fmaxf(tmax, __shfl_xor(tmax, 8));
      float mnew = fmaxf(m_r[r], tmax);
      float ssum = expf(sv[0][r] - mnew) + expf(sv[1][r] - mnew) + expf(sv[2][r] - mnew) +
                   expf(sv[3][r] - mnew);
      ssum += __shfl_xor(ssum, 1);
      ssum += __shfl_xor(ssum, 2);
      ssum += __shfl_xor(ssum, 4);
      ssum += __shfl_xor(ssum, 8);
      l_r[r] = l_r[r] * expf(m_r[r] - mnew) + ssum;
      m_r[r] = mnew;
    }
  }
  float inv_l[4];
#pragma unroll
  for (int r = 0; r < 4; r++) inv_l[r] = 1.0f / l_r[r];

  floatx4 o[8] = {};
  // ---- loop 2: exact normalized p, colsums, PV ----
  for (int kt = 0; kt < nkt; kt++) {
    const int k0 = kt * 64;
    __syncthreads();
#pragma unroll
    for (int i = 0; i < 4; i++) {
      int id = tid + i * 256;
      int r = id >> 4, c = id & 15;
      size_t goff = (size_t)(k0 + r) * DMODEL + h * HDIM + c * 8;
      int didx = r * 128 + ((c * 8) ^ ((r & 7) << 3));
      *reinterpret_cast<short8v*>(&KaS[didx]) = *reinterpret_cast<const short8v*>(&Ka[goff]);
      *reinterpret_cast<short8v*>(&KbS[didx]) = *reinterpret_cast<const short8v*>(&Kb[goff]);
      *reinterpret_cast<short8v*>(&KcS[didx]) = *reinterpret_cast<const short8v*>(&Kc[goff]);
    }
    __syncthreads();
    float pv[4][4];
#pragma unroll
    for (int ct = 0; ct < 4; ct++) {
      floatx4 sacc = {};
      const int krow = ct * 16 + ln;
#pragma unroll
      for (int dc = 0; dc < 4; dc++) {
        int didx = krow * 128 + ((dc * 32 + g * 8) ^ ((krow & 7) << 3));
        short8v k1 = *reinterpret_cast<const short8v*>(&KaS[didx]);
        short8v k2 = *reinterpret_cast<const short8v*>(&KbS[didx]);
        short8v k3 = *reinterpret_cast<const short8v*>(&KcS[didx]);
        sacc = __builtin_amdgcn_mfma_f32_16x16x32_bf16(q1[dc], k1, sacc, 0, 0, 0);
        sacc = __builtin_amdgcn_mfma_f32_16x16x32_bf16(q1[dc], k2, sacc, 0, 0, 0);
        sacc = __builtin_amdgcn_mfma_f32_16x16x32_bf16(q2[dc], k1, sacc, 0, 0, 0);
        sacc = __builtin_amdgcn_mfma_f32_16x16x32_bf16(q1[dc], k3, sacc, 0, 0, 0);
        sacc = __builtin_amdgcn_mfma_f32_16x16x32_bf16(q2[dc], k2, sacc, 0, 0, 0);
        sacc = __builtin_amdgcn_mfma_f32_16x16x32_bf16(q3[dc], k1, sacc, 0, 0, 0);
      }
#pragma unroll
      for (int r = 0; r < 4; r++) {
        float s = sacc[r] * ATTN_SCALE;
        int key = k0 + ct * 16 + ln;
        int qq = q0 + w * 16 + g * 4 + r;
        s = (key <= qq) ? s : NEGBIG;
        pv[ct][r] = expf(s - m_r[r]) * inv_l[r];
      }
    }
#pragma unroll
    for (int ct = 0; ct < 4; ct++) {
      float c2 = pv[ct][0] + pv[ct][1] + pv[ct][2] + pv[ct][3];
      c2 += __shfl_xor(c2, 16);
      c2 += __shfl_xor(c2, 32);
      if (g == 0) cs[w][ct * 16 + ln] = c2;
    }
#pragma unroll
    for (int ct = 0; ct < 4; ct++)
#pragma unroll
      for (int r = 0; r < 4; r++) {
        int prow = g * 4 + r, pcol = ct * 16 + ln;
        Ps[w * 1024 + prow * 64 + (pcol ^ (((prow >> 2) & 3) << 4))] = (short)f2bf(pv[ct][r]);
      }
    __syncthreads();
    if (tid < 64)
      score_part[((size_t)blockIdx.x * NH + h) * S_LEN + k0 + tid] =
          cs[0][tid] + cs[1][tid] + cs[2][tid] + cs[3][tid];
#pragma unroll
    for (int kc = 0; kc < 2; kc++) {
      short8v pa = *reinterpret_cast<const short8v*>(
          &Ps[w * 1024 + ln * 64 + ((kc * 32 + g * 8) ^ (((ln >> 2) & 3) << 4))]);
#pragma unroll
      for (int ctd = 0; ctd < 8; ctd++) {
        size_t voff = ((size_t)h * HDIM + ctd * 16 + ln) * S_LEN + k0 + kc * 32 + g * 8;
        short8v vb = *reinterpret_cast<const short8v*>(&Vt[voff]);
        o[ctd] = __builtin_amdgcn_mfma_f32_16x16x32_bf16(pa, vb, o[ctd], 0, 0, 0);
      }
    }
  }
#pragma unroll
  for (int ctd = 0; ctd < 8; ctd++)
#pragma unroll
    for (int r = 0; r < 4; r++)
      AO[(size_t)(q0 + w * 16 + g * 4 + r) * DMODEL + h * HDIM + ctd * 16 + ln] = o[ctd][r];
}

// ---------------- reduce column-sum partials ----------------
__global__ void reduce_scores(const float* __restrict__ score_part, float* __restrict__ scores) {
  int idx = blockIdx.x * blockDim.x + threadIdx.x;
  if (idx >= NH * S_LEN) return;
  int h = idx >> 11, k = idx & 2047;
  float s = 0.f;
  for (int qb = 0; qb < 32; qb++) s += score_part[((size_t)qb * NH + h) * S_LEN + k];
  scores[idx] = s;
}

// ---------------- per-head exact top-256 + mask + previous_scores ----------------
__global__ __launch_bounds__(256) void topk_mask_kernel(const float* __restrict__ scores,
                                                        float* __restrict__ out_mask,
                                                        float* __restrict__ prev_scores) {
  const int h = blockIdx.x;
  __shared__ unsigned sb[S_LEN - RECENT];
  __shared__ int cnt_sh;
  const int NSEL = S_LEN - RECENT;
  const int tid = threadIdx.x;
  const float* sc = scores + (size_t)h * S_LEN;
  for (int i = tid; i < NSEL; i += 256) sb[i] = __float_as_uint(sc[i]);
  __syncthreads();
  unsigned prefix = 0u;
  for (int b = 31; b >= 0; b--) {
    unsigned cand = prefix | (1u << b);
    if (tid == 0) cnt_sh = 0;
    __syncthreads();
    int c = 0;
    for (int i = tid; i < NSEL; i += 256) c += (sb[i] >= cand) ? 1 : 0;
    atomicAdd(&cnt_sh, c);
    __syncthreads();
    if (cnt_sh >= HEAVY) prefix = cand;
    __syncthreads();
  }
  if (tid == 0) cnt_sh = 0;
  __syncthreads();
  int c = 0;
  for (int i = tid; i < NSEL; i += 256) c += (sb[i] > prefix) ? 1 : 0;
  atomicAdd(&cnt_sh, c);
  __syncthreads();
  const int c1 = cnt_sh;
  float* mrow = out_mask + (size_t)h * (S_LEN + 1);
  float* prow = prev_scores + (size_t)h * S_LEN;
  for (int j = NSEL + tid; j < S_LEN + 1; j += 256) mrow[j] = 1.0f;
  for (int k = NSEL + tid; k < S_LEN; k += 256) prow[k] = sc[k];
  for (int i = tid; i < NSEL; i += 256) {
    bool sel = sb[i] > prefix;
    mrow[i] = sel ? 1.f : 0.f;
    prow[i] = sel ? sc[i] : 0.f;
  }
  __syncthreads();
  if (tid == 0) {
    int need = HEAVY - c1;
    for (int i = 0; i < NSEL && need > 0; i++) {
      if (sb[i] == prefix) { mrow[i] = 1.f; prow[i] = sc[i]; need--; }
    }
  }
}

extern "C" void kernel_launch(void* const* d_in, const int* in_sizes, int n_in,
                              void* d_out, int out_size, void* d_ws, size_t ws_size,
                              hipStream_t stream) {
  const float* hidden = (const float*)d_in[0];
  const int* pos = (const int*)d_in[2];
  const float* Wq = (const float*)d_in[3];
  const float* Wk = (const float*)d_in[4];
  const float* Wv = (const float*)d_in[5];
  const float* Wo = (const float*)d_in[6];

  float* out0 = (float*)d_out;
  float* out_mask = out0 + (size_t)S_LEN * DMODEL;
  float* prev_scores = out_mask + (size_t)NH * (S_LEN + 1);

  char* ws = (char*)d_ws;
  float* Qf = (float*)(ws + 0 * MB);     // 32MB -> AO after rope
  float* Kf = (float*)(ws + 32 * MB);    // 32MB -> score_part/scores after rope
  ushort* Vt = (ushort*)(ws + 64 * MB);  // 16MB, direct from V-proj GEMM
  short* Qa = (short*)(ws + 80 * MB);
  short* Qb = (short*)(ws + 96 * MB);
  short* Qc = (short*)(ws + 112 * MB);
  short* Ka = (short*)(ws + 128 * MB);
  short* Kb = (short*)(ws + 144 * MB);
  short* Kc = (short*)(ws + 160 * MB);   // ends at 176MB
  float* AO = Qf;
  float* score_part = (float*)(ws + 32 * MB);  // 8MB
  float* scores = (float*)(ws + 41 * MB);      // 256KB

  dim3 gg(DMODEL / 128, S_LEN / 128);
  gemm6<<<gg, 256, 0, stream>>>(hidden, Wq, Qf, S_LEN, DMODEL, DMODEL);
  gemm6<<<gg, 256, 0, stream>>>(hidden, Wk, Kf, S_LEN, DMODEL, DMODEL);
  gemm_vbt<<<gg, 256, 0, stream>>>(hidden, Wv, Vt, S_LEN, DMODEL, DMODEL);

  int rope_total = S_LEN * NH * 64;
  rope_convert<<<(rope_total + 255) / 256, 256, 0, stream>>>(Qf, Kf, pos, Qa, Qb, Qc, Ka, Kb, Kc);

  hipError_t _e = hipMemsetAsync(score_part, 0, (size_t)32 * NH * S_LEN * sizeof(float), stream);
  (void)_e;
  attn_all6<<<dim3(S_LEN / 64, NH), 256, 0, stream>>>(Qa, Qb, Qc, Ka, Kb, Kc, Vt, AO, score_part);

  reduce_scores<<<(NH * S_LEN + 255) / 256, 256, 0, stream>>>(score_part, scores);
  topk_mask_kernel<<<NH, 256, 0, stream>>>(scores, out_mask, prev_scores);

  gemm_bf1<<<gg, 256, 0, stream>>>(AO, Wo, out0, S_LEN, DMODEL, DMODEL);
}

// Round 5
// 1763.057 us; speedup vs baseline: 4.2404x; 1.1801x over previous
//
#include <hip/hip_runtime.h>
#include <hip/hip_bf16.h>
#include <cmath>

#define S_LEN 2048
#define DMODEL 4096
#define NH 32
#define HDIM 128
#define HEAVY 256
#define RECENT 256
#define ATTN_SCALE 0.08838834764831845f  // 1/sqrt(128)
#define NEGBIG -3.0e38f
#define MB (1024ull * 1024ull)

typedef __attribute__((ext_vector_type(8))) short short8v;
typedef __attribute__((ext_vector_type(4))) short short4v;
typedef __attribute__((ext_vector_type(4))) float floatx4;

__device__ inline ushort f2bf(float x) {
  __hip_bfloat16 h = __float2bfloat16(x);
  return __builtin_bit_cast(ushort, h);
}
__device__ inline float bf2f(ushort u) {
  __hip_bfloat16 h = __builtin_bit_cast(__hip_bfloat16, u);
  return __bfloat162float(h);
}
struct Split3 {
  short a, b, c;
};
__device__ inline Split3 split3(float x) {
  Split3 o;
  ushort u1 = f2bf(x);
  float r1 = x - bf2f(u1);
  ushort u2 = f2bf(r1);
  float r2 = r1 - bf2f(u2);
  ushort u3 = f2bf(r2);
  o.a = (short)u1;
  o.b = (short)u2;
  o.c = (short)u3;
  return o;
}

// ===== 6-product (3-way split) fp32-class GEMM: C[M][N] = A[M][K]*B[N][K]^T =====
__global__ __launch_bounds__(256) void gemm6(const float* __restrict__ A,
                                             const float* __restrict__ B,
                                             float* __restrict__ C, int M, int N, int K) {
  __shared__ short Aa[128 * 40], Ab[128 * 40], Ac[128 * 40];
  __shared__ short Ba[128 * 40], Bb[128 * 40], Bc[128 * 40];
  const int tid = threadIdx.x;
  const int w = tid >> 6, l = tid & 63, g = l >> 4, ln = l & 15;
  const int wm = w >> 1, wn = w & 1;
  const int row0 = blockIdx.y * 128, col0 = blockIdx.x * 128;
  floatx4 acc[4][4] = {};
  for (int k0 = 0; k0 < K; k0 += 32) {
    __syncthreads();
#pragma unroll
    for (int i = 0; i < 4; i++) {
      int id = tid + i * 256;
      int r = id >> 3, c4 = id & 7;
      float4 av = *reinterpret_cast<const float4*>(&A[(size_t)(row0 + r) * K + k0 + c4 * 4]);
      float4 bv = *reinterpret_cast<const float4*>(&B[(size_t)(col0 + r) * K + k0 + c4 * 4]);
      float af[4] = {av.x, av.y, av.z, av.w};
      float bf[4] = {bv.x, bv.y, bv.z, bv.w};
      short4v a1, a2, a3, b1, b2, b3;
#pragma unroll
      for (int j = 0; j < 4; j++) {
        Split3 sa = split3(af[j]);
        Split3 sb = split3(bf[j]);
        a1[j] = sa.a; a2[j] = sa.b; a3[j] = sa.c;
        b1[j] = sb.a; b2[j] = sb.b; b3[j] = sb.c;
      }
      int o = r * 40 + c4 * 4;
      *reinterpret_cast<short4v*>(&Aa[o]) = a1;
      *reinterpret_cast<short4v*>(&Ab[o]) = a2;
      *reinterpret_cast<short4v*>(&Ac[o]) = a3;
      *reinterpret_cast<short4v*>(&Ba[o]) = b1;
      *reinterpret_cast<short4v*>(&Bb[o]) = b2;
      *reinterpret_cast<short4v*>(&Bc[o]) = b3;
    }
    __syncthreads();
#pragma unroll
    for (int i = 0; i < 4; i++) {
      int ar = (wm * 64 + i * 16 + ln) * 40 + g * 8;
      short8v a1 = *reinterpret_cast<const short8v*>(&Aa[ar]);
      short8v a2 = *reinterpret_cast<const short8v*>(&Ab[ar]);
      short8v a3 = *reinterpret_cast<const short8v*>(&Ac[ar]);
#pragma unroll
      for (int j = 0; j < 4; j++) {
        int br = (wn * 64 + j * 16 + ln) * 40 + g * 8;
        short8v b1 = *reinterpret_cast<const short8v*>(&Ba[br]);
        short8v b2 = *reinterpret_cast<const short8v*>(&Bb[br]);
        short8v b3 = *reinterpret_cast<const short8v*>(&Bc[br]);
        acc[i][j] = __builtin_amdgcn_mfma_f32_16x16x32_bf16(a1, b1, acc[i][j], 0, 0, 0);
        acc[i][j] = __builtin_amdgcn_mfma_f32_16x16x32_bf16(a1, b2, acc[i][j], 0, 0, 0);
        acc[i][j] = __builtin_amdgcn_mfma_f32_16x16x32_bf16(a2, b1, acc[i][j], 0, 0, 0);
        acc[i][j] = __builtin_amdgcn_mfma_f32_16x16x32_bf16(a1, b3, acc[i][j], 0, 0, 0);
        acc[i][j] = __builtin_amdgcn_mfma_f32_16x16x32_bf16(a2, b2, acc[i][j], 0, 0, 0);
        acc[i][j] = __builtin_amdgcn_mfma_f32_16x16x32_bf16(a3, b1, acc[i][j], 0, 0, 0);
      }
    }
  }
#pragma unroll
  for (int i = 0; i < 4; i++)
#pragma unroll
    for (int j = 0; j < 4; j++)
#pragma unroll
      for (int r = 0; r < 4; r++)
        C[(size_t)(row0 + wm * 64 + i * 16 + g * 4 + r) * N + col0 + wn * 64 + j * 16 + ln] =
            acc[i][j][r];
}

// ===== plain bf16 GEMM, fp32 out (Wo) =====
__global__ __launch_bounds__(256) void gemm_bf1(const float* __restrict__ A,
                                                const float* __restrict__ B,
                                                float* __restrict__ C, int M, int N, int K) {
  __shared__ short Ah[128 * 40];
  __shared__ short Bh[128 * 40];
  const int tid = threadIdx.x;
  const int w = tid >> 6, l = tid & 63, g = l >> 4, ln = l & 15;
  const int wm = w >> 1, wn = w & 1;
  const int row0 = blockIdx.y * 128, col0 = blockIdx.x * 128;
  floatx4 acc[4][4] = {};
  for (int k0 = 0; k0 < K; k0 += 32) {
    __syncthreads();
#pragma unroll
    for (int i = 0; i < 4; i++) {
      int id = tid + i * 256;
      int r = id >> 3, c4 = id & 7;
      float4 av = *reinterpret_cast<const float4*>(&A[(size_t)(row0 + r) * K + k0 + c4 * 4]);
      float4 bv = *reinterpret_cast<const float4*>(&B[(size_t)(col0 + r) * K + k0 + c4 * 4]);
      short4v ah, bh;
      ah[0] = (short)f2bf(av.x); ah[1] = (short)f2bf(av.y);
      ah[2] = (short)f2bf(av.z); ah[3] = (short)f2bf(av.w);
      bh[0] = (short)f2bf(bv.x); bh[1] = (short)f2bf(bv.y);
      bh[2] = (short)f2bf(bv.z); bh[3] = (short)f2bf(bv.w);
      *reinterpret_cast<short4v*>(&Ah[r * 40 + c4 * 4]) = ah;
      *reinterpret_cast<short4v*>(&Bh[r * 40 + c4 * 4]) = bh;
    }
    __syncthreads();
#pragma unroll
    for (int i = 0; i < 4; i++) {
      short8v a = *reinterpret_cast<const short8v*>(&Ah[(wm * 64 + i * 16 + ln) * 40 + g * 8]);
#pragma unroll
      for (int j = 0; j < 4; j++) {
        short8v b = *reinterpret_cast<const short8v*>(&Bh[(wn * 64 + j * 16 + ln) * 40 + g * 8]);
        acc[i][j] = __builtin_amdgcn_mfma_f32_16x16x32_bf16(a, b, acc[i][j], 0, 0, 0);
      }
    }
  }
#pragma unroll
  for (int i = 0; i < 4; i++)
#pragma unroll
    for (int j = 0; j < 4; j++)
#pragma unroll
      for (int r = 0; r < 4; r++)
        C[(size_t)(row0 + wm * 64 + i * 16 + g * 4 + r) * N + col0 + wn * 64 + j * 16 + ln] =
            acc[i][j][r];
}

// ===== plain bf16 GEMM, transposed bf16 out: Vt[n][m] = (A*B^T)[m][n] =====
__global__ __launch_bounds__(256) void gemm_vbt(const float* __restrict__ A,
                                                const float* __restrict__ B,
                                                ushort* __restrict__ Vt, int M, int N, int K) {
  __shared__ short Ah[128 * 40];
  __shared__ short Bh[128 * 40];
  const int tid = threadIdx.x;
  const int w = tid >> 6, l = tid & 63, g = l >> 4, ln = l & 15;
  const int wm = w >> 1, wn = w & 1;
  const int row0 = blockIdx.y * 128, col0 = blockIdx.x * 128;
  floatx4 acc[4][4] = {};
  for (int k0 = 0; k0 < K; k0 += 32) {
    __syncthreads();
#pragma unroll
    for (int i = 0; i < 4; i++) {
      int id = tid + i * 256;
      int r = id >> 3, c4 = id & 7;
      float4 av = *reinterpret_cast<const float4*>(&A[(size_t)(row0 + r) * K + k0 + c4 * 4]);
      float4 bv = *reinterpret_cast<const float4*>(&B[(size_t)(col0 + r) * K + k0 + c4 * 4]);
      short4v ah, bh;
      ah[0] = (short)f2bf(av.x); ah[1] = (short)f2bf(av.y);
      ah[2] = (short)f2bf(av.z); ah[3] = (short)f2bf(av.w);
      bh[0] = (short)f2bf(bv.x); bh[1] = (short)f2bf(bv.y);
      bh[2] = (short)f2bf(bv.z); bh[3] = (short)f2bf(bv.w);
      *reinterpret_cast<short4v*>(&Ah[r * 40 + c4 * 4]) = ah;
      *reinterpret_cast<short4v*>(&Bh[r * 40 + c4 * 4]) = bh;
    }
    __syncthreads();
#pragma unroll
    for (int i = 0; i < 4; i++) {
      short8v a = *reinterpret_cast<const short8v*>(&Ah[(wm * 64 + i * 16 + ln) * 40 + g * 8]);
#pragma unroll
      for (int j = 0; j < 4; j++) {
        short8v b = *reinterpret_cast<const short8v*>(&Bh[(wn * 64 + j * 16 + ln) * 40 + g * 8]);
        acc[i][j] = __builtin_amdgcn_mfma_f32_16x16x32_bf16(a, b, acc[i][j], 0, 0, 0);
      }
    }
  }
#pragma unroll
  for (int i = 0; i < 4; i++)
#pragma unroll
    for (int j = 0; j < 4; j++) {
      short4v o;
#pragma unroll
      for (int r = 0; r < 4; r++) o[r] = (short)f2bf(acc[i][j][r]);
      size_t n = col0 + wn * 64 + j * 16 + ln;
      size_t m0 = row0 + wm * 64 + i * 16 + g * 4;
      *reinterpret_cast<short4v*>(&Vt[n * M + m0]) = o;
    }
}

// ===== RoPE + 3-way split of Q,K (one fp64 pow per (r,d), loop over h) =====
__global__ void rope_convert(const float* __restrict__ Q, const float* __restrict__ K,
                             const int* __restrict__ pos, short* __restrict__ Qa,
                             short* __restrict__ Qb, short* __restrict__ Qc,
                             short* __restrict__ Ka, short* __restrict__ Kb,
                             short* __restrict__ Kc) {
  int idx = blockIdx.x * blockDim.x + threadIdx.x;
  if (idx >= S_LEN * 64) return;
  int d = idx & 63;
  int r = idx >> 6;
  float p = (float)pos[r];
  float invf = (float)pow(10000.0, -(double)(2 * d) / 128.0);
  float ang = p * invf;
  float c = cosf(ang), s = sinf(ang);
  for (int h = 0; h < NH; h++) {
    size_t base = (size_t)r * DMODEL + h * HDIM + d;
    float q1 = Q[base], q2 = Q[base + 64];
    float k1 = K[base], k2 = K[base + 64];
    float qa = q1 * c - q2 * s, qb = q2 * c + q1 * s;
    float ka = k1 * c - k2 * s, kb = k2 * c + k1 * s;
    Split3 t;
    t = split3(qa); Qa[base] = t.a; Qb[base] = t.b; Qc[base] = t.c;
    t = split3(qb); Qa[base + 64] = t.a; Qb[base + 64] = t.b; Qc[base + 64] = t.c;
    t = split3(ka); Ka[base] = t.a; Kb[base] = t.b; Kc[base] = t.c;
    t = split3(kb); Ka[base + 64] = t.a; Kb[base + 64] = t.b; Kc[base + 64] = t.c;
  }
}

// ===== fused flash attention v2: paired q-blocks, KVBLK=32, double-buffered =====
#define KVB 32
#define KTILE_SH (KVB * 128)  // shorts per split per buffer

__device__ __forceinline__ floatx4 qk6_tile(const short* KaS, const short* KbS,
                                            const short* KcS, const short8v q1[4],
                                            const short8v q2[4], const short8v q3[4],
                                            int krow, int g) {
  floatx4 sacc = {};
#pragma unroll
  for (int dc = 0; dc < 4; dc++) {
    int didx = krow * 128 + ((dc * 32 + g * 8) ^ ((krow & 7) << 3));
    short8v k1 = *reinterpret_cast<const short8v*>(&KaS[didx]);
    short8v k2 = *reinterpret_cast<const short8v*>(&KbS[didx]);
    short8v k3 = *reinterpret_cast<const short8v*>(&KcS[didx]);
    sacc = __builtin_amdgcn_mfma_f32_16x16x32_bf16(q1[dc], k1, sacc, 0, 0, 0);
    sacc = __builtin_amdgcn_mfma_f32_16x16x32_bf16(q1[dc], k2, sacc, 0, 0, 0);
    sacc = __builtin_amdgcn_mfma_f32_16x16x32_bf16(q2[dc], k1, sacc, 0, 0, 0);
    sacc = __builtin_amdgcn_mfma_f32_16x16x32_bf16(q1[dc], k3, sacc, 0, 0, 0);
    sacc = __builtin_amdgcn_mfma_f32_16x16x32_bf16(q2[dc], k2, sacc, 0, 0, 0);
    sacc = __builtin_amdgcn_mfma_f32_16x16x32_bf16(q3[dc], k1, sacc, 0, 0, 0);
  }
  return sacc;
}

__device__ __forceinline__ void stage_load(const short* __restrict__ Ka,
                                           const short* __restrict__ Kb,
                                           const short* __restrict__ Kc, int k0, int h, int tid,
                                           short8v sA[2], short8v sB[2], short8v sC[2]) {
#pragma unroll
  for (int i = 0; i < 2; i++) {
    int id = tid + i * 256;
    int r = id >> 4, c = id & 15;
    size_t goff = (size_t)(k0 + r) * DMODEL + h * HDIM + c * 8;
    sA[i] = *reinterpret_cast<const short8v*>(&Ka[goff]);
    sB[i] = *reinterpret_cast<const short8v*>(&Kb[goff]);
    sC[i] = *reinterpret_cast<const short8v*>(&Kc[goff]);
  }
}

__device__ __forceinline__ void stage_store(short* KaS, short* KbS, short* KcS, int tid,
                                            const short8v sA[2], const short8v sB[2],
                                            const short8v sC[2]) {
#pragma unroll
  for (int i = 0; i < 2; i++) {
    int id = tid + i * 256;
    int r = id >> 4, c = id & 15;
    int didx = r * 128 + ((c * 8) ^ ((r & 7) << 3));
    *reinterpret_cast<short8v*>(&KaS[didx]) = sA[i];
    *reinterpret_cast<short8v*>(&KbS[didx]) = sB[i];
    *reinterpret_cast<short8v*>(&KcS[didx]) = sC[i];
  }
}

__device__ void process_qblock(int qb, int h, const short* __restrict__ Qa,
                               const short* __restrict__ Qb, const short* __restrict__ Qc,
                               const short* __restrict__ Ka, const short* __restrict__ Kb,
                               const short* __restrict__ Kc, const ushort* __restrict__ Vt,
                               float* __restrict__ AO, float* __restrict__ sp4, short* KS0,
                               short* Ps, int tid, int w, int g, int ln) {
  const int q0 = qb * 64;
  const int qrow = q0 + w * 16 + ln;
  short8v q1[4], q2[4], q3[4];
#pragma unroll
  for (int dc = 0; dc < 4; dc++) {
    size_t off = (size_t)qrow * DMODEL + h * HDIM + dc * 32 + g * 8;
    q1[dc] = *reinterpret_cast<const short8v*>(&Qa[off]);
    q2[dc] = *reinterpret_cast<const short8v*>(&Qb[off]);
    q3[dc] = *reinterpret_cast<const short8v*>(&Qc[off]);
  }
  float m_r[4], l_r[4];
#pragma unroll
  for (int r = 0; r < 4; r++) { m_r[r] = NEGBIG; l_r[r] = 0.f; }
  const int nkt = 2 * qb + 2;
  short8v sA[2], sB[2], sC[2];

  // ---- pass 1: exact per-row max & sum ----
  stage_load(Ka, Kb, Kc, 0, h, tid, sA, sB, sC);
  stage_store(KS0 + 0, KS0 + KTILE_SH, KS0 + 2 * KTILE_SH, tid, sA, sB, sC);
  __syncthreads();
  for (int t = 0; t < nkt; t++) {
    const int k0 = t * KVB;
    const int cur = t & 1, nxt = cur ^ 1;
    const bool pre = (t + 1 < nkt);
    if (pre) stage_load(Ka, Kb, Kc, k0 + KVB, h, tid, sA, sB, sC);
    short* KaS = KS0 + cur * 3 * KTILE_SH;
    float sv[2][4];
#pragma unroll
    for (int ct = 0; ct < 2; ct++) {
      floatx4 sacc = qk6_tile(KaS, KaS + KTILE_SH, KaS + 2 * KTILE_SH, q1, q2, q3, ct * 16 + ln, g);
#pragma unroll
      for (int r = 0; r < 4; r++) {
        float s = sacc[r] * ATTN_SCALE;
        int key = k0 + ct * 16 + ln;
        int qq = q0 + w * 16 + g * 4 + r;
        sv[ct][r] = (key <= qq) ? s : NEGBIG;
      }
    }
#pragma unroll
    for (int r = 0; r < 4; r++) {
      float tmax = fmaxf(sv[0][r], sv[1][r]);
      tmax = fmaxf(tmax, __shfl_xor(tmax, 1));
      tmax = fmaxf(tmax, __shfl_xor(tmax, 2));
      tmax = fmaxf(tmax, __shfl_xor(tmax, 4));
      tmax = fmaxf(tmax, __shfl_xor(tmax, 8));
      float mnew = fmaxf(m_r[r], tmax);
      float ssum = __expf(sv[0][r] - mnew) + __expf(sv[1][r] - mnew);
      ssum += __shfl_xor(ssum, 1);
      ssum += __shfl_xor(ssum, 2);
      ssum += __shfl_xor(ssum, 4);
      ssum += __shfl_xor(ssum, 8);
      l_r[r] = l_r[r] * __expf(m_r[r] - mnew) + ssum;
      m_r[r] = mnew;
    }
    if (pre) {
      short* KaN = KS0 + nxt * 3 * KTILE_SH;
      stage_store(KaN, KaN + KTILE_SH, KaN + 2 * KTILE_SH, tid, sA, sB, sC);
    }
    __syncthreads();
  }
  float inv_l[4];
#pragma unroll
  for (int r = 0; r < 4; r++) inv_l[r] = 1.0f / l_r[r];

  // ---- pass 2: normalized p, colsums, PV ----
  floatx4 o[8] = {};
  stage_load(Ka, Kb, Kc, 0, h, tid, sA, sB, sC);
  stage_store(KS0 + 0, KS0 + KTILE_SH, KS0 + 2 * KTILE_SH, tid, sA, sB, sC);
  __syncthreads();
  for (int t = 0; t < nkt; t++) {
    const int k0 = t * KVB;
    const int cur = t & 1, nxt = cur ^ 1;
    const bool pre = (t + 1 < nkt);
    if (pre) stage_load(Ka, Kb, Kc, k0 + KVB, h, tid, sA, sB, sC);
    short* KaS = KS0 + cur * 3 * KTILE_SH;
    float pv[2][4];
#pragma unroll
    for (int ct = 0; ct < 2; ct++) {
      floatx4 sacc = qk6_tile(KaS, KaS + KTILE_SH, KaS + 2 * KTILE_SH, q1, q2, q3, ct * 16 + ln, g);
#pragma unroll
      for (int r = 0; r < 4; r++) {
        float s = sacc[r] * ATTN_SCALE;
        int key = k0 + ct * 16 + ln;
        int qq = q0 + w * 16 + g * 4 + r;
        s = (key <= qq) ? s : NEGBIG;
        pv[ct][r] = __expf(s - m_r[r]) * inv_l[r];
      }
    }
    // per-wave column sums straight to global (deterministic)
#pragma unroll
    for (int ct = 0; ct < 2; ct++) {
      float c2 = pv[ct][0] + pv[ct][1] + pv[ct][2] + pv[ct][3];
      c2 += __shfl_xor(c2, 16);
      c2 += __shfl_xor(c2, 32);
      if (g == 0) sp4[((size_t)(qb * 4 + w) * NH + h) * S_LEN + k0 + ct * 16 + ln] = c2;
    }
    // P -> bf16 -> per-wave swizzled LDS (C-frag -> A-frag relayout)
#pragma unroll
    for (int ct = 0; ct < 2; ct++)
#pragma unroll
      for (int r = 0; r < 4; r++) {
        int prow = g * 4 + r, pcol = ct * 16 + ln;
        Ps[w * 512 + prow * 32 + (pcol ^ (((prow >> 1) & 1) << 4))] = (short)f2bf(pv[ct][r]);
      }
    // PV: O[16q][128d] += P[16][32] * V[32][128]
    short8v pa = *reinterpret_cast<const short8v*>(
        &Ps[w * 512 + ln * 32 + ((g * 8) ^ (((ln >> 1) & 1) << 4))]);
#pragma unroll
    for (int ctd = 0; ctd < 8; ctd++) {
      size_t voff = ((size_t)h * HDIM + ctd * 16 + ln) * S_LEN + k0 + g * 8;
      short8v vb = *reinterpret_cast<const short8v*>(&Vt[voff]);
      o[ctd] = __builtin_amdgcn_mfma_f32_16x16x32_bf16(pa, vb, o[ctd], 0, 0, 0);
    }
    if (pre) {
      short* KaN = KS0 + nxt * 3 * KTILE_SH;
      stage_store(KaN, KaN + KTILE_SH, KaN + 2 * KTILE_SH, tid, sA, sB, sC);
    }
    __syncthreads();
  }
#pragma unroll
  for (int ctd = 0; ctd < 8; ctd++)
#pragma unroll
    for (int r = 0; r < 4; r++)
      AO[(size_t)(q0 + w * 16 + g * 4 + r) * DMODEL + h * HDIM + ctd * 16 + ln] = o[ctd][r];
}

__global__ __launch_bounds__(256) void attn_fused(
    const short* __restrict__ Qa, const short* __restrict__ Qb, const short* __restrict__ Qc,
    const short* __restrict__ Ka, const short* __restrict__ Kb, const short* __restrict__ Kc,
    const ushort* __restrict__ Vt, float* __restrict__ AO, float* __restrict__ sp4) {
  __shared__ short KS[2 * 3 * KTILE_SH];  // 48KB double-buffered K splits
  __shared__ short Ps[4 * 512];           // 4KB per-wave P tiles
  const int bid = blockIdx.x;
  const int pid = bid >> 5, h = bid & 31;
  const int tid = threadIdx.x;
  const int w = tid >> 6, l = tid & 63, g = l >> 4, ln = l & 15;
  (void)l;
  process_qblock(31 - pid, h, Qa, Qb, Qc, Ka, Kb, Kc, Vt, AO, sp4, KS, Ps, tid, w, g, ln);
  process_qblock(pid, h, Qa, Qb, Qc, Ka, Kb, Kc, Vt, AO, sp4, KS, Ps, tid, w, g, ln);
}

// ---------------- reduce column-sum partials (128 per (h,k)) ----------------
__global__ void reduce_scores(const float* __restrict__ sp4, float* __restrict__ scores) {
  int idx = blockIdx.x * blockDim.x + threadIdx.x;
  if (idx >= NH * S_LEN) return;
  int h = idx >> 11, k = idx & 2047;
  float s = 0.f;
  for (int j = 0; j < 128; j++) s += sp4[((size_t)j * NH + h) * S_LEN + k];
  scores[idx] = s;
}

// ---------------- per-head exact top-256 + mask + previous_scores ----------------
__global__ __launch_bounds__(256) void topk_mask_kernel(const float* __restrict__ scores,
                                                        float* __restrict__ out_mask,
                                                        float* __restrict__ prev_scores) {
  const int h = blockIdx.x;
  __shared__ unsigned sb[S_LEN - RECENT];
  __shared__ int cnt_sh;
  const int NSEL = S_LEN - RECENT;
  const int tid = threadIdx.x;
  const float* sc = scores + (size_t)h * S_LEN;
  for (int i = tid; i < NSEL; i += 256) sb[i] = __float_as_uint(sc[i]);
  __syncthreads();
  unsigned prefix = 0u;
  for (int b = 31; b >= 0; b--) {
    unsigned cand = prefix | (1u << b);
    if (tid == 0) cnt_sh = 0;
    __syncthreads();
    int c = 0;
    for (int i = tid; i < NSEL; i += 256) c += (sb[i] >= cand) ? 1 : 0;
    atomicAdd(&cnt_sh, c);
    __syncthreads();
    if (cnt_sh >= HEAVY) prefix = cand;
    __syncthreads();
  }
  if (tid == 0) cnt_sh = 0;
  __syncthreads();
  int c = 0;
  for (int i = tid; i < NSEL; i += 256) c += (sb[i] > prefix) ? 1 : 0;
  atomicAdd(&cnt_sh, c);
  __syncthreads();
  const int c1 = cnt_sh;
  float* mrow = out_mask + (size_t)h * (S_LEN + 1);
  float* prow = prev_scores + (size_t)h * S_LEN;
  for (int j = NSEL + tid; j < S_LEN + 1; j += 256) mrow[j] = 1.0f;
  for (int k = NSEL + tid; k < S_LEN; k += 256) prow[k] = sc[k];
  for (int i = tid; i < NSEL; i += 256) {
    bool sel = sb[i] > prefix;
    mrow[i] = sel ? 1.f : 0.f;
    prow[i] = sel ? sc[i] : 0.f;
  }
  __syncthreads();
  if (tid == 0) {
    int need = HEAVY - c1;
    for (int i = 0; i < NSEL && need > 0; i++) {
      if (sb[i] == prefix) { mrow[i] = 1.f; prow[i] = sc[i]; need--; }
    }
  }
}

extern "C" void kernel_launch(void* const* d_in, const int* in_sizes, int n_in,
                              void* d_out, int out_size, void* d_ws, size_t ws_size,
                              hipStream_t stream) {
  const float* hidden = (const float*)d_in[0];
  const int* pos = (const int*)d_in[2];
  const float* Wq = (const float*)d_in[3];
  const float* Wk = (const float*)d_in[4];
  const float* Wv = (const float*)d_in[5];
  const float* Wo = (const float*)d_in[6];

  float* out0 = (float*)d_out;
  float* out_mask = out0 + (size_t)S_LEN * DMODEL;
  float* prev_scores = out_mask + (size_t)NH * (S_LEN + 1);

  char* ws = (char*)d_ws;
  float* Qf = (float*)(ws + 0 * MB);     // 32MB -> AO after rope
  float* Kf = (float*)(ws + 32 * MB);    // 32MB -> sp4 after rope
  ushort* Vt = (ushort*)(ws + 64 * MB);  // 16MB -> scores region after attn
  short* Qa = (short*)(ws + 80 * MB);
  short* Qb = (short*)(ws + 96 * MB);
  short* Qc = (short*)(ws + 112 * MB);
  short* Ka = (short*)(ws + 128 * MB);
  short* Kb = (short*)(ws + 144 * MB);
  short* Kc = (short*)(ws + 160 * MB);  // ends at 176MB
  float* AO = Qf;
  float* sp4 = Kf;                       // 128*32*2048*4B = 32MB exactly
  float* scores = (float*)(ws + 64 * MB);  // Vt dead after attn; 256KB

  dim3 gg(DMODEL / 128, S_LEN / 128);
  gemm6<<<gg, 256, 0, stream>>>(hidden, Wq, Qf, S_LEN, DMODEL, DMODEL);
  gemm6<<<gg, 256, 0, stream>>>(hidden, Wk, Kf, S_LEN, DMODEL, DMODEL);
  gemm_vbt<<<gg, 256, 0, stream>>>(hidden, Wv, Vt, S_LEN, DMODEL, DMODEL);

  int rope_total = S_LEN * 64;
  rope_convert<<<(rope_total + 255) / 256, 256, 0, stream>>>(Qf, Kf, pos, Qa, Qb, Qc, Ka, Kb, Kc);

  hipError_t _e = hipMemsetAsync(sp4, 0, (size_t)128 * NH * S_LEN * sizeof(float), stream);
  (void)_e;
  attn_fused<<<512, 256, 0, stream>>>(Qa, Qb, Qc, Ka, Kb, Kc, Vt, AO, sp4);

  reduce_scores<<<(NH * S_LEN + 255) / 256, 256, 0, stream>>>(sp4, scores);
  topk_mask_kernel<<<NH, 256, 0, stream>>>(scores, out_mask, prev_scores);

  gemm_bf1<<<gg, 256, 0, stream>>>(AO, Wo, out0, S_LEN, DMODEL, DMODEL);
}